// Round 10
// baseline (538.099 us; speedup 1.0000x reference)
//
#include <hip/hip_runtime.h>
#include <hip/hip_cooperative_groups.h>
#include <math.h>

namespace cg = cooperative_groups;

// B=4, H=W=64, C=128, NH=4, HD=32, K=7, TOK=16384
#define TOK 16384

typedef __attribute__((ext_vector_type(8))) __bf16 bf16x8;
typedef __attribute__((ext_vector_type(4))) float f32x4;

__device__ inline unsigned short f2bf(float f) {
    union { float f; unsigned int u; } v; v.f = f;
    unsigned int r = v.u + 0x7fffu + ((v.u >> 16) & 1u);
    return (unsigned short)(r >> 16);
}
__device__ inline float gelu_exact(float v) {
    return 0.5f * v * (1.0f + erff(v * 0.70710678118654752f));
}

// =================== Phase bodies (shared by fused + fallback) ==============

// ---- P0: tiled weight transpose to bf16 (blocks 0..191) --------------------
__device__ __forceinline__ void wtrans_body(
    const float* __restrict__ Wq, const float* __restrict__ Wkv,
    const float* __restrict__ Wp, const float* __restrict__ W1, const float* __restrict__ W2,
    unsigned short* __restrict__ Wt, float* tile /*32*33 f32*/, int t, int tid)
{
    const float* src; unsigned short* dst; int Kd, Nd, li;
    if      (t < 16)  { src = Wq;  dst = Wt;          Kd = 128; Nd = 128; li = t; }
    else if (t < 48)  { src = Wkv; dst = Wt + 16384;  Kd = 128; Nd = 256; li = t - 16; }
    else if (t < 64)  { src = Wp;  dst = Wt + 49152;  Kd = 128; Nd = 128; li = t - 48; }
    else if (t < 128) { src = W1;  dst = Wt + 65536;  Kd = 128; Nd = 512; li = t - 64; }
    else              { src = W2;  dst = Wt + 131072; Kd = 512; Nd = 128; li = t - 128; }
    int ntc = Nd >> 5;
    int k0 = (li / ntc) * 32, n0 = (li % ntc) * 32;
    int r = tid >> 3, c4 = (tid & 7) * 4;
    float4 v = *(const float4*)(src + (size_t)(k0 + r) * Nd + n0 + c4);
    tile[r * 33 + c4 + 0] = v.x; tile[r * 33 + c4 + 1] = v.y;
    tile[r * 33 + c4 + 2] = v.z; tile[r * 33 + c4 + 3] = v.w;
    __syncthreads();
    ushort4 o;
    o.x = f2bf(tile[(c4 + 0) * 33 + r]);
    o.y = f2bf(tile[(c4 + 1) * 33 + r]);
    o.z = f2bf(tile[(c4 + 2) * 33 + r]);
    o.w = f2bf(tile[(c4 + 3) * 33 + r]);
    *(ushort4*)(dst + (size_t)(n0 + r) * Kd + k0 + c4) = o;
}

// ---- P1: fused LN1/LN2 + QKV projection (16 tokens/block) ------------------
__device__ __forceinline__ void qkvln_body(
    const float* __restrict__ query, const float* __restrict__ key_value,
    const float* __restrict__ g1, const float* __restrict__ b1,
    const float* __restrict__ g2, const float* __restrict__ b2,
    const unsigned short* __restrict__ Wt,   // WtQ @0, WtKV @+16384
    const float* __restrict__ bq, const float* __restrict__ bkv,
    unsigned short* __restrict__ qbh, unsigned short* __restrict__ kbh,
    unsigned short* __restrict__ vbh, float qscale,
    unsigned short* aq /*16*136*/, unsigned short* akv /*16*136*/, int bid, int tid)
{
    const int wave = tid >> 6, lane = tid & 63;
    const int lr = lane & 15, lg = lane >> 4;
    const int m0 = bid * 16;
    {
        const int r = tid >> 4, t16 = tid & 15;
#pragma unroll
        for (int which = 0; which < 2; ++which) {
            const float* xr = (which ? key_value : query) + (size_t)(m0 + r) * 128 + t16 * 8;
            float4 v0 = *(const float4*)xr;
            float4 v1 = *(const float4*)(xr + 4);
            float s = v0.x + v0.y + v0.z + v0.w + v1.x + v1.y + v1.z + v1.w;
            s += __shfl_xor(s, 1); s += __shfl_xor(s, 2);
            s += __shfl_xor(s, 4); s += __shfl_xor(s, 8);
            float mean = s * (1.0f / 128.0f);
            float d0 = v0.x - mean, d1 = v0.y - mean, d2 = v0.z - mean, d3 = v0.w - mean;
            float d4 = v1.x - mean, d5 = v1.y - mean, d6 = v1.z - mean, d7 = v1.w - mean;
            float vv = d0*d0 + d1*d1 + d2*d2 + d3*d3 + d4*d4 + d5*d5 + d6*d6 + d7*d7;
            vv += __shfl_xor(vv, 1); vv += __shfl_xor(vv, 2);
            vv += __shfl_xor(vv, 4); vv += __shfl_xor(vv, 8);
            float rs = rsqrtf(vv * (1.0f / 128.0f) + 1e-5f);
            const float* g = which ? g2 : g1;
            const float* bb = which ? b2 : b1;
            float4 ga = *(const float4*)(g + t16 * 8);
            float4 gb = *(const float4*)(g + t16 * 8 + 4);
            float4 ba = *(const float4*)(bb + t16 * 8);
            float4 bbb = *(const float4*)(bb + t16 * 8 + 4);
            ushort4 oa, ob;
            oa.x = f2bf(d0 * rs * ga.x + ba.x); oa.y = f2bf(d1 * rs * ga.y + ba.y);
            oa.z = f2bf(d2 * rs * ga.z + ba.z); oa.w = f2bf(d3 * rs * ga.w + ba.w);
            ob.x = f2bf(d4 * rs * gb.x + bbb.x); ob.y = f2bf(d5 * rs * gb.y + bbb.y);
            ob.z = f2bf(d6 * rs * gb.z + bbb.z); ob.w = f2bf(d7 * rs * gb.w + bbb.w);
            unsigned short* dst = (which ? akv : aq) + r * 136 + t16 * 8;
            *(ushort4*)dst = oa;
            *(ushort4*)(dst + 4) = ob;
        }
    }
    __syncthreads();
#pragma unroll
    for (int t = 0; t < 6; ++t) {
        int j = wave + 4 * t;
        const unsigned short* A = (j < 8) ? aq : akv;
        const unsigned short* Wb = (j < 8) ? (Wt + (size_t)(j * 16 + lr) * 128)
                                           : (Wt + 16384 + (size_t)((j - 8) * 16 + lr) * 128);
        f32x4 acc = {0.f, 0.f, 0.f, 0.f};
#pragma unroll
        for (int kk = 0; kk < 4; ++kk) {
            bf16x8 af = *(const bf16x8*)&A[lr * 136 + kk * 32 + lg * 8];
            bf16x8 wf = *(const bf16x8*)(Wb + kk * 32 + lg * 8);
            acc = __builtin_amdgcn_mfma_f32_16x16x32_bf16(af, wf, acc, 0, 0, 0);
        }
        if (j < 8) {
            int gc = j * 16 + lr;
            float bs = bq[gc];
#pragma unroll
            for (int r = 0; r < 4; ++r)
                qbh[(size_t)(m0 + lg * 4 + r) * 128 + gc] = f2bf((acc[r] + bs) * qscale);
        } else {
            int gc = (j - 8) * 16 + lr;
            float bs = bkv[gc];
            if (gc < 128) {
#pragma unroll
                for (int r = 0; r < 4; ++r)
                    kbh[(size_t)(m0 + lg * 4 + r) * 128 + gc] = f2bf(acc[r] + bs);
            } else {
#pragma unroll
                for (int r = 0; r < 4; ++r)
                    vbh[(size_t)(m0 + lg * 4 + r) * 128 + gc - 128] = f2bf(acc[r] + bs);
            }
        }
    }
}

// ---- P2: neighborhood attention (R9-verified, 32 KB LDS) -------------------
__device__ __forceinline__ void attn_body(
    const unsigned short* __restrict__ qbh, const unsigned short* __restrict__ kbh,
    const unsigned short* __restrict__ vbh, const float* __restrict__ rpb,
    unsigned short* __restrict__ out, unsigned short* shm /*16384 ushorts*/,
    int bid, int tid)
{
    unsigned short* kS = shm;              // [224][40]
    unsigned short* vT = shm + 8960;       // [32][232]
    unsigned short* Pb = shm;              // [64][72] (post-QK overlay)
    float* rpbs = (float*)(shm + 4608);    // 169 f32 (post-QK overlay)
    const int wave = tid >> 6, lane = tid & 63;
    const int lr = lane & 15, lg = lane >> 4;
    const int tile = bid & 63, h = (bid >> 6) & 3, b = bid >> 8;
    const int ti0 = (tile >> 3) * 8, tj0 = (tile & 7) * 8;
    const int hr0 = min(max(ti0 - 3, 0), 50);
    const int hc0 = min(max(tj0 - 3, 0), 50);
    const int bb = b << 12;

    for (int u = tid; u < 896; u += 256) {
        int tok = u >> 2, chunk = u & 3;
        int tr = tok >> 4, tc = tok & 15;
        size_t src = (size_t)(bb + (hr0 + tr) * 64 + hc0 + tc) * 128 + h * 32 + chunk * 8;
        int4 kw = *(const int4*)(kbh + src);
        *(int4*)&kS[tok * 40 + chunk * 8] = kw;
        int4 vw = *(const int4*)(vbh + src);
        const unsigned short* v8 = (const unsigned short*)&vw;
#pragma unroll
        for (int k = 0; k < 8; ++k)
            vT[(chunk * 8 + k) * 232 + tok] = v8[k];
    }
    const int gi_m = ti0 + wave * 2 + (lr >> 3);
    const int gj_m = tj0 + (lr & 7);
    const int tq = bb + gi_m * 64 + gj_m;
    bf16x8 qf = *(const bf16x8*)(qbh + (size_t)tq * 128 + h * 32 + lg * 8);
    __syncthreads();

    f32x4 S[14];
#pragma unroll
    for (int kb = 0; kb < 14; ++kb) {
        bf16x8 kf = *(const bf16x8*)&kS[(kb * 16 + lr) * 40 + lg * 8];
        f32x4 z = {0.f, 0.f, 0.f, 0.f};
        S[kb] = __builtin_amdgcn_mfma_f32_16x16x32_bf16(qf, kf, z, 0, 0, 0);
    }
    __syncthreads();

    if (tid < 169) rpbs[tid] = rpb[h * 169 + tid];
    __syncthreads();

#pragma unroll
    for (int i = 0; i < 4; ++i) {
        int m = lg * 4 + i;
        int gi = ti0 + wave * 2 + (m >> 3);
        int gj = tj0 + (m & 7);
        int si = min(max(gi - 3, 0), 57), sj = min(max(gj - 3, 0), 57);
        bool cv = (unsigned)(hc0 + lr - sj) < 7u;
        int rjc = min(max(hc0 + lr - gj + 6, 0), 12);
        float mxi = -INFINITY;
#pragma unroll
        for (int kb = 0; kb < 14; ++kb) {
            bool rv = (unsigned)(hr0 + kb - si) < 7u;
            int ric = min(max(hr0 + kb - gi + 6, 0), 12);
            float bias = rpbs[rjc + ric * 13];
            float s = (rv && cv) ? S[kb][i] + bias : -1e30f;
            S[kb][i] = s;
            mxi = fmaxf(mxi, s);
        }
        mxi = fmaxf(mxi, __shfl_xor(mxi, 1));
        mxi = fmaxf(mxi, __shfl_xor(mxi, 2));
        mxi = fmaxf(mxi, __shfl_xor(mxi, 4));
        mxi = fmaxf(mxi, __shfl_xor(mxi, 8));
        float smi = 0.0f;
#pragma unroll
        for (int kb = 0; kb < 14; ++kb) {
            float e = __expf(S[kb][i] - mxi);
            S[kb][i] = e;
            smi += e;
        }
        smi += __shfl_xor(smi, 1);
        smi += __shfl_xor(smi, 2);
        smi += __shfl_xor(smi, 4);
        smi += __shfl_xor(smi, 8);
        float rinv = 1.0f / smi;
#pragma unroll
        for (int kb = 0; kb < 14; ++kb) S[kb][i] *= rinv;
    }

    f32x4 O[2] = {};
#pragma unroll
    for (int r = 0; r < 4; ++r) {
        const int nk = (r < 3) ? 4 : 2;
#pragma unroll
        for (int i = 0; i < 4; ++i) {
            int m = lg * 4 + i;
#pragma unroll
            for (int kbl = 0; kbl < 4; ++kbl) {
                if (kbl < nk)
                    Pb[(wave * 16 + m) * 72 + kbl * 16 + lr] = f2bf(S[r * 4 + kbl][i]);
            }
        }
#pragma unroll
        for (int ksl = 0; ksl < 2; ++ksl) {
            if (ksl * 2 < nk) {
                bf16x8 pf = *(const bf16x8*)&Pb[(wave * 16 + lr) * 72 + ksl * 32 + lg * 8];
#pragma unroll
                for (int nb = 0; nb < 2; ++nb) {
                    bf16x8 vf = *(const bf16x8*)&vT[(nb * 16 + lr) * 232 + r * 64 + ksl * 32 + lg * 8];
                    O[nb] = __builtin_amdgcn_mfma_f32_16x16x32_bf16(pf, vf, O[nb], 0, 0, 0);
                }
            }
        }
    }
#pragma unroll
    for (int i = 0; i < 4; ++i) {
        int m = lg * 4 + i;
        int gi = ti0 + wave * 2 + (m >> 3);
        int gj = tj0 + (m & 7);
        size_t t = ((size_t)(bb + gi * 64 + gj)) * 128 + h * 32;
        out[t + lr]      = f2bf(O[0][i]);
        out[t + 16 + lr] = f2bf(O[1][i]);
    }
}

// ---- P3: tail = Wp + res + LN3 + W1 + GELU + W2 + res (16 tokens/block) ----
__device__ __forceinline__ void tail_body(
    const unsigned short* __restrict__ attnh,
    const unsigned short* __restrict__ WtP, const unsigned short* __restrict__ W1t,
    const unsigned short* __restrict__ W2t,
    const float* __restrict__ bp, const float* __restrict__ bm1, const float* __restrict__ bm2,
    const float* __restrict__ resk, const float* __restrict__ g3, const float* __restrict__ b3,
    float* __restrict__ dout, unsigned char* smem, int bid, int tid)
{
    float* xs = (float*)smem;                             // [16][132] f32 (8448 B)
    unsigned short* xnS = (unsigned short*)(smem + 8448); // [16][136]  (4352 B)
    unsigned short* hS  = (unsigned short*)(smem + 12800);// [16][520]  (16640 B)
    const int wave = tid >> 6, lane = tid & 63;
    const int lr = lane & 15, lg = lane >> 4;
    const int m0 = bid * 16;

#pragma unroll
    for (int t = 0; t < 2; ++t) {
        int colt = wave + 4 * t;
        int tok = m0 + lr;
        f32x4 acc = {0.f, 0.f, 0.f, 0.f};
#pragma unroll
        for (int kk = 0; kk < 4; ++kk) {
            bf16x8 af = *(const bf16x8*)(attnh + (size_t)tok * 128 + kk * 32 + lg * 8);
            bf16x8 wf = *(const bf16x8*)(WtP + (size_t)(colt * 16 + lr) * 128 + kk * 32 + lg * 8);
            acc = __builtin_amdgcn_mfma_f32_16x16x32_bf16(af, wf, acc, 0, 0, 0);
        }
        int gc = colt * 16 + lr;
        float bs = bp[gc];
#pragma unroll
        for (int r = 0; r < 4; ++r) {
            int row = lg * 4 + r;
            xs[row * 132 + gc] = acc[r] + bs + resk[(size_t)(m0 + row) * 128 + gc];
        }
    }
    __syncthreads();
    {
        const int r = tid >> 4, t16 = tid & 15;
        float vals[8];
#pragma unroll
        for (int jj = 0; jj < 8; ++jj) vals[jj] = xs[r * 132 + t16 * 8 + jj];
        float s = 0.0f;
#pragma unroll
        for (int jj = 0; jj < 8; ++jj) s += vals[jj];
        s += __shfl_xor(s, 1); s += __shfl_xor(s, 2);
        s += __shfl_xor(s, 4); s += __shfl_xor(s, 8);
        float mean = s * (1.0f / 128.0f);
        float vv = 0.0f;
#pragma unroll
        for (int jj = 0; jj < 8; ++jj) { float d = vals[jj] - mean; vv += d * d; }
        vv += __shfl_xor(vv, 1); vv += __shfl_xor(vv, 2);
        vv += __shfl_xor(vv, 4); vv += __shfl_xor(vv, 8);
        float rs = rsqrtf(vv * (1.0f / 128.0f) + 1e-5f);
        float4 ga = *(const float4*)(g3 + t16 * 8);
        float4 gb = *(const float4*)(g3 + t16 * 8 + 4);
        float4 ba = *(const float4*)(b3 + t16 * 8);
        float4 bbv = *(const float4*)(b3 + t16 * 8 + 4);
        ushort4 oa, ob;
        oa.x = f2bf((vals[0] - mean) * rs * ga.x + ba.x);
        oa.y = f2bf((vals[1] - mean) * rs * ga.y + ba.y);
        oa.z = f2bf((vals[2] - mean) * rs * ga.z + ba.z);
        oa.w = f2bf((vals[3] - mean) * rs * ga.w + ba.w);
        ob.x = f2bf((vals[4] - mean) * rs * gb.x + bbv.x);
        ob.y = f2bf((vals[5] - mean) * rs * gb.y + bbv.y);
        ob.z = f2bf((vals[6] - mean) * rs * gb.z + bbv.z);
        ob.w = f2bf((vals[7] - mean) * rs * gb.w + bbv.w);
        *(ushort4*)&xnS[r * 136 + t16 * 8] = oa;
        *(ushort4*)&xnS[r * 136 + t16 * 8 + 4] = ob;
    }
    __syncthreads();
#pragma unroll
    for (int t = 0; t < 8; ++t) {
        int colt = wave + 4 * t;
        f32x4 acc = {0.f, 0.f, 0.f, 0.f};
#pragma unroll
        for (int kk = 0; kk < 4; ++kk) {
            bf16x8 wf = *(const bf16x8*)(W1t + (size_t)(colt * 16 + lr) * 128 + kk * 32 + lg * 8);
            bf16x8 xf = *(const bf16x8*)&xnS[lr * 136 + kk * 32 + lg * 8];
            acc = __builtin_amdgcn_mfma_f32_16x16x32_bf16(wf, xf, acc, 0, 0, 0);
        }
        int chb = colt * 16 + lg * 4;
        float4 bs = *(const float4*)(bm1 + chb);
        ushort4 pk;
        pk.x = f2bf(gelu_exact(acc[0] + bs.x));
        pk.y = f2bf(gelu_exact(acc[1] + bs.y));
        pk.z = f2bf(gelu_exact(acc[2] + bs.z));
        pk.w = f2bf(gelu_exact(acc[3] + bs.w));
        *(ushort4*)&hS[lr * 520 + chb] = pk;
    }
    __syncthreads();
#pragma unroll
    for (int t = 0; t < 2; ++t) {
        int colt = wave + 4 * t;
        f32x4 acc = {0.f, 0.f, 0.f, 0.f};
#pragma unroll
        for (int kk = 0; kk < 16; ++kk) {
            bf16x8 hf = *(const bf16x8*)&hS[lr * 520 + kk * 32 + lg * 8];
            bf16x8 wf = *(const bf16x8*)(W2t + (size_t)(colt * 16 + lr) * 512 + kk * 32 + lg * 8);
            acc = __builtin_amdgcn_mfma_f32_16x16x32_bf16(hf, wf, acc, 0, 0, 0);
        }
        int gc = colt * 16 + lr;
        float bs = bm2[gc];
#pragma unroll
        for (int r = 0; r < 4; ++r) {
            int row = lg * 4 + r;
            dout[(size_t)(m0 + row) * 128 + gc] = acc[r] + bs + xs[row * 132 + gc];
        }
    }
}

// =================== Fused cooperative kernel ===============================
struct KParams {
    const float *query, *key_value, *g1, *b1, *g2, *b2, *g3, *b3;
    const float *Wq, *bq, *Wkv, *bkv, *Wp, *bp, *rpb, *W1, *bm1, *W2, *bm2;
    unsigned short *qbh, *kbh, *vbh, *attnh, *Wt;
    float *dout;
    float qscale;
};

__global__ __launch_bounds__(256, 4) void fused_kernel(KParams p)
{
    __shared__ __align__(16) unsigned char smem[32768];
    cg::grid_group grid = cg::this_grid();
    const int tid = threadIdx.x, bid = blockIdx.x;

    if (bid < 192)
        wtrans_body(p.Wq, p.Wkv, p.Wp, p.W1, p.W2, p.Wt, (float*)smem, bid, tid);
    grid.sync();
    qkvln_body(p.query, p.key_value, p.g1, p.b1, p.g2, p.b2, p.Wt, p.bq, p.bkv,
               p.qbh, p.kbh, p.vbh, p.qscale,
               (unsigned short*)smem, (unsigned short*)smem + 2176, bid, tid);
    grid.sync();
    attn_body(p.qbh, p.kbh, p.vbh, p.rpb, p.attnh, (unsigned short*)smem, bid, tid);
    grid.sync();
    tail_body(p.attnh, p.Wt + 49152, p.Wt + 65536, p.Wt + 131072,
              p.bp, p.bm1, p.bm2, p.key_value, p.g3, p.b3, p.dout, smem, bid, tid);
}

// =================== Fallback 4-dispatch kernels (R9-identical) =============
__global__ __launch_bounds__(256) void wtrans_kernel(
    const float* Wq, const float* Wkv, const float* Wp, const float* W1, const float* W2,
    unsigned short* Wt)
{
    __shared__ float tile[32 * 33];
    wtrans_body(Wq, Wkv, Wp, W1, W2, Wt, tile, blockIdx.x, threadIdx.x);
}
__global__ __launch_bounds__(256) void qkvln_kernel(
    const float* query, const float* key_value,
    const float* g1, const float* b1, const float* g2, const float* b2,
    const unsigned short* Wt, const float* bq, const float* bkv,
    unsigned short* qbh, unsigned short* kbh, unsigned short* vbh, float qscale)
{
    __shared__ __align__(16) unsigned short s[4352];
    qkvln_body(query, key_value, g1, b1, g2, b2, Wt, bq, bkv, qbh, kbh, vbh, qscale,
               s, s + 2176, blockIdx.x, threadIdx.x);
}
__global__ __launch_bounds__(256, 4) void nat_attn(
    const unsigned short* qbh, const unsigned short* kbh, const unsigned short* vbh,
    const float* rpb, unsigned short* out)
{
    __shared__ __align__(16) unsigned short shm[16384];
    attn_body(qbh, kbh, vbh, rpb, out, shm, blockIdx.x, threadIdx.x);
}
__global__ __launch_bounds__(256) void tail_kernel(
    const unsigned short* attnh, const unsigned short* WtP, const unsigned short* W1t,
    const unsigned short* W2t, const float* bp, const float* bm1, const float* bm2,
    const float* resk, const float* g3, const float* b3, float* dout)
{
    __shared__ __align__(16) unsigned char smem[29440];
    tail_body(attnh, WtP, W1t, W2t, bp, bm1, bm2, resk, g3, b3, dout,
              smem, blockIdx.x, threadIdx.x);
}

extern "C" void kernel_launch(void* const* d_in, const int* in_sizes, int n_in,
                              void* d_out, int out_size, void* d_ws, size_t ws_size,
                              hipStream_t stream) {
    const float* query     = (const float*)d_in[0];
    const float* key_value = (const float*)d_in[1];
    const float* g1 = (const float*)d_in[2];
    const float* b1 = (const float*)d_in[3];
    const float* g2 = (const float*)d_in[4];
    const float* b2 = (const float*)d_in[5];
    const float* g3 = (const float*)d_in[6];
    const float* b3 = (const float*)d_in[7];
    const float* Wq  = (const float*)d_in[8];
    const float* bq  = (const float*)d_in[9];
    const float* Wkv = (const float*)d_in[10];
    const float* bkv = (const float*)d_in[11];
    const float* Wp  = (const float*)d_in[12];
    const float* bp  = (const float*)d_in[13];
    const float* rpb = (const float*)d_in[14];
    const float* W1  = (const float*)d_in[15];
    const float* bm1 = (const float*)d_in[16];
    const float* W2  = (const float*)d_in[17];
    const float* bm2 = (const float*)d_in[18];

    char* ws = (char*)d_ws;
    unsigned short* qbh   = (unsigned short*)(ws + 0);         // 4 MB bf16 [TOK][128]
    unsigned short* kbh   = (unsigned short*)(ws + 4194304);   // 4 MB bf16 [TOK][128]
    unsigned short* vbh   = (unsigned short*)(ws + 8388608);   // 4 MB bf16 [TOK][128]
    unsigned short* attnh = (unsigned short*)(ws + 12582912);  // 4 MB bf16 [TOK][128]
    unsigned short* Wt    = (unsigned short*)(ws + 16777216);  // 384 KB bf16 transposed
    // attn halo staging may read <=2 tokens past kbh/vbh -> lands in vbh/attnh
    // (mapped workspace, finite bf16, masked before softmax)

    const float qscale = 0.17677669529663687f;  // HD^-0.5

    KParams p;
    p.query = query; p.key_value = key_value;
    p.g1 = g1; p.b1 = b1; p.g2 = g2; p.b2 = b2; p.g3 = g3; p.b3 = b3;
    p.Wq = Wq; p.bq = bq; p.Wkv = Wkv; p.bkv = bkv; p.Wp = Wp; p.bp = bp;
    p.rpb = rpb; p.W1 = W1; p.bm1 = bm1; p.W2 = W2; p.bm2 = bm2;
    p.qbh = qbh; p.kbh = kbh; p.vbh = vbh; p.attnh = attnh; p.Wt = Wt;
    p.dout = (float*)d_out; p.qscale = qscale;

    void* args[] = { (void*)&p };
    hipError_t err = hipLaunchCooperativeKernel((const void*)fused_kernel,
                                                dim3(1024), dim3(256), args, 0, stream);
    if (err != hipSuccess) {
        // deterministic fallback: identical 4-dispatch pipeline (R9)
        wtrans_kernel<<<192, 256, 0, stream>>>(Wq, Wkv, Wp, W1, W2, Wt);
        qkvln_kernel<<<1024, 256, 0, stream>>>(query, key_value, g1, b1, g2, b2,
                                               Wt, bq, bkv, qbh, kbh, vbh, qscale);
        nat_attn<<<1024, 256, 0, stream>>>(qbh, kbh, vbh, rpb, attnh);
        tail_kernel<<<1024, 256, 0, stream>>>(attnh, Wt + 49152, Wt + 65536, Wt + 131072,
                                              bp, bm1, bm2, key_value, g3, b3, (float*)d_out);
    }
}

// Round 11
// 165.262 us; speedup vs baseline: 3.2560x; 3.2560x over previous
//
#include <hip/hip_runtime.h>
#include <math.h>

// B=4, H=W=64, C=128, NH=4, HD=32, K=7, TOK=16384
#define TOK 16384

typedef __attribute__((ext_vector_type(8))) __bf16 bf16x8;
typedef __attribute__((ext_vector_type(4))) float f32x4;

__device__ inline unsigned short f2bf(float f) {
    union { float f; unsigned int u; } v; v.f = f;
    unsigned int r = v.u + 0x7fffu + ((v.u >> 16) & 1u);
    return (unsigned short)(r >> 16);
}
__device__ inline float gelu_exact(float v) {
    return 0.5f * v * (1.0f + erff(v * 0.70710678118654752f));
}

// ---------------- D1: tiled weight transpose to bf16 (192 blocks) -----------
__global__ __launch_bounds__(256) void wtrans_kernel(
    const float* __restrict__ Wq, const float* __restrict__ Wkv,
    const float* __restrict__ Wp, const float* __restrict__ W1, const float* __restrict__ W2,
    unsigned short* __restrict__ Wt)
{
    __shared__ float tile[32][33];
    int t = blockIdx.x, tid = threadIdx.x;
    const float* src; unsigned short* dst; int Kd, Nd, li;
    if      (t < 16)  { src = Wq;  dst = Wt;          Kd = 128; Nd = 128; li = t; }
    else if (t < 48)  { src = Wkv; dst = Wt + 16384;  Kd = 128; Nd = 256; li = t - 16; }
    else if (t < 64)  { src = Wp;  dst = Wt + 49152;  Kd = 128; Nd = 128; li = t - 48; }
    else if (t < 128) { src = W1;  dst = Wt + 65536;  Kd = 128; Nd = 512; li = t - 64; }
    else              { src = W2;  dst = Wt + 131072; Kd = 512; Nd = 128; li = t - 128; }
    int ntc = Nd >> 5;
    int k0 = (li / ntc) * 32, n0 = (li % ntc) * 32;
    int r = tid >> 3, c4 = (tid & 7) * 4;
    float4 v = *(const float4*)(src + (size_t)(k0 + r) * Nd + n0 + c4);
    tile[r][c4 + 0] = v.x; tile[r][c4 + 1] = v.y;
    tile[r][c4 + 2] = v.z; tile[r][c4 + 3] = v.w;
    __syncthreads();
    ushort4 o;
    o.x = f2bf(tile[c4 + 0][r]);
    o.y = f2bf(tile[c4 + 1][r]);
    o.z = f2bf(tile[c4 + 2][r]);
    o.w = f2bf(tile[c4 + 3][r]);
    *(ushort4*)(dst + (size_t)(n0 + r) * Kd + k0 + c4) = o;
}

// ---------------- D2: fused LN1/LN2 + QKV projection ------------------------
// 1024 blocks x 4 waves, 16 tokens each. LN into LDS bf16, then 24 16x16 jobs.
__global__ __launch_bounds__(256) void qkvln_kernel(
    const float* __restrict__ query, const float* __restrict__ key_value,
    const float* __restrict__ g1, const float* __restrict__ b1,
    const float* __restrict__ g2, const float* __restrict__ b2,
    const unsigned short* __restrict__ Wt,   // WtQ @0, WtKV @+16384
    const float* __restrict__ bq, const float* __restrict__ bkv,
    unsigned short* __restrict__ qbh, unsigned short* __restrict__ kbh,
    unsigned short* __restrict__ vbh, float qscale)
{
    __shared__ __align__(16) unsigned short aq[16 * 136];
    __shared__ __align__(16) unsigned short akv[16 * 136];
    const int tid = threadIdx.x;
    const int wave = tid >> 6, lane = tid & 63;
    const int lr = lane & 15, lg = lane >> 4;
    const int m0 = blockIdx.x * 16;

    {
        const int r = tid >> 4, t16 = tid & 15;
#pragma unroll
        for (int which = 0; which < 2; ++which) {
            const float* xr = (which ? key_value : query) + (size_t)(m0 + r) * 128 + t16 * 8;
            float4 v0 = *(const float4*)xr;
            float4 v1 = *(const float4*)(xr + 4);
            float s = v0.x + v0.y + v0.z + v0.w + v1.x + v1.y + v1.z + v1.w;
            s += __shfl_xor(s, 1); s += __shfl_xor(s, 2);
            s += __shfl_xor(s, 4); s += __shfl_xor(s, 8);
            float mean = s * (1.0f / 128.0f);
            float d0 = v0.x - mean, d1 = v0.y - mean, d2 = v0.z - mean, d3 = v0.w - mean;
            float d4 = v1.x - mean, d5 = v1.y - mean, d6 = v1.z - mean, d7 = v1.w - mean;
            float vv = d0*d0 + d1*d1 + d2*d2 + d3*d3 + d4*d4 + d5*d5 + d6*d6 + d7*d7;
            vv += __shfl_xor(vv, 1); vv += __shfl_xor(vv, 2);
            vv += __shfl_xor(vv, 4); vv += __shfl_xor(vv, 8);
            float rs = rsqrtf(vv * (1.0f / 128.0f) + 1e-5f);
            const float* g = which ? g2 : g1;
            const float* bb = which ? b2 : b1;
            float4 ga = *(const float4*)(g + t16 * 8);
            float4 gb = *(const float4*)(g + t16 * 8 + 4);
            float4 ba = *(const float4*)(bb + t16 * 8);
            float4 bbb = *(const float4*)(bb + t16 * 8 + 4);
            ushort4 oa, ob;
            oa.x = f2bf(d0 * rs * ga.x + ba.x); oa.y = f2bf(d1 * rs * ga.y + ba.y);
            oa.z = f2bf(d2 * rs * ga.z + ba.z); oa.w = f2bf(d3 * rs * ga.w + ba.w);
            ob.x = f2bf(d4 * rs * gb.x + bbb.x); ob.y = f2bf(d5 * rs * gb.y + bbb.y);
            ob.z = f2bf(d6 * rs * gb.z + bbb.z); ob.w = f2bf(d7 * rs * gb.w + bbb.w);
            unsigned short* dst = (which ? akv : aq) + r * 136 + t16 * 8;
            *(ushort4*)dst = oa;
            *(ushort4*)(dst + 4) = ob;
        }
    }
    __syncthreads();

#pragma unroll
    for (int t = 0; t < 6; ++t) {
        int j = wave + 4 * t;
        const unsigned short* A = (j < 8) ? aq : akv;
        const unsigned short* Wb = (j < 8) ? (Wt + (size_t)(j * 16 + lr) * 128)
                                           : (Wt + 16384 + (size_t)((j - 8) * 16 + lr) * 128);
        f32x4 acc = {0.f, 0.f, 0.f, 0.f};
#pragma unroll
        for (int kk = 0; kk < 4; ++kk) {
            bf16x8 af = *(const bf16x8*)&A[lr * 136 + kk * 32 + lg * 8];
            bf16x8 wf = *(const bf16x8*)(Wb + kk * 32 + lg * 8);
            acc = __builtin_amdgcn_mfma_f32_16x16x32_bf16(af, wf, acc, 0, 0, 0);
        }
        if (j < 8) {
            int gc = j * 16 + lr;
            float bs = bq[gc];
#pragma unroll
            for (int r = 0; r < 4; ++r)
                qbh[(size_t)(m0 + lg * 4 + r) * 128 + gc] = f2bf((acc[r] + bs) * qscale);
        } else {
            int gc = (j - 8) * 16 + lr;
            float bs = bkv[gc];
            if (gc < 128) {
#pragma unroll
                for (int r = 0; r < 4; ++r)
                    kbh[(size_t)(m0 + lg * 4 + r) * 128 + gc] = f2bf(acc[r] + bs);
            } else {
#pragma unroll
                for (int r = 0; r < 4; ++r)
                    vbh[(size_t)(m0 + lg * 4 + r) * 128 + gc - 128] = f2bf(acc[r] + bs);
            }
        }
    }
}

// ---------------- D3: neighborhood attention (33.5 KB LDS, 4 blocks/CU) -----
// vs R9: dedicated rpbs (one fewer barrier), vT XOR swizzle (4-way -> 2-way
// bank conflicts), softmax normalization deferred to O-epilogue.
__global__ __launch_bounds__(256, 4) void nat_attn(
    const unsigned short* __restrict__ qbh,   // [TOK][128] bf16 (pre-scaled)
    const unsigned short* __restrict__ kbh,   // [TOK][128] bf16
    const unsigned short* __restrict__ vbh,   // [TOK][128] bf16
    const float* __restrict__ rpb,            // [4][13][13]
    unsigned short* __restrict__ out)         // [TOK][128] bf16
{
    __shared__ __align__(16) unsigned short shm[16384];   // kS/Pb + vT
    __shared__ float rpbs[169];                           // dedicated (no overlay)
    unsigned short* kS = shm;              // [224][40]
    unsigned short* vT = shm + 8960;       // [32][232], tok XOR-swizzled
    unsigned short* Pb = shm;              // [64][72] (post-QK overlay of kS)
    const int tid = threadIdx.x;
    const int wave = tid >> 6, lane = tid & 63;
    const int lr = lane & 15, lg = lane >> 4;
    const int bid = blockIdx.x;
    const int tile = bid & 63, h = (bid >> 6) & 3, b = bid >> 8;
    const int ti0 = (tile >> 3) * 8, tj0 = (tile & 7) * 8;
    const int hr0 = min(max(ti0 - 3, 0), 50);
    const int hc0 = min(max(tj0 - 3, 0), 50);
    const int bb = b << 12;

    if (tid < 169) rpbs[tid] = rpb[h * 169 + tid];

    // ---- stage K (pos-major) and V (transposed, swizzled) into LDS
    for (int u = tid; u < 896; u += 256) {
        int tok = u >> 2, chunk = u & 3;
        int tr = tok >> 4, tc = tok & 15;
        size_t src = (size_t)(bb + (hr0 + tr) * 64 + hc0 + tc) * 128 + h * 32 + chunk * 8;
        int4 kw = *(const int4*)(kbh + src);
        *(int4*)&kS[tok * 40 + chunk * 8] = kw;
        int4 vw = *(const int4*)(vbh + src);
        const unsigned short* v8 = (const unsigned short*)&vw;
        int tsw = tok ^ (chunk << 3);   // bits 3-4 only; stays < 224
#pragma unroll
        for (int k = 0; k < 8; ++k)
            vT[(chunk * 8 + k) * 232 + tsw] = v8[k];
    }

    // ---- Q A-frag from global (m = lr)
    const int gi_m = ti0 + wave * 2 + (lr >> 3);
    const int gj_m = tj0 + (lr & 7);
    const int tq = bb + gi_m * 64 + gj_m;
    bf16x8 qf = *(const bf16x8*)(qbh + (size_t)tq * 128 + h * 32 + lg * 8);
    __syncthreads();

    // ---- QK^T: 14 MFMAs from LDS
    f32x4 S[14];
#pragma unroll
    for (int kb = 0; kb < 14; ++kb) {
        bf16x8 kf = *(const bf16x8*)&kS[(kb * 16 + lr) * 40 + lg * 8];
        f32x4 z = {0.f, 0.f, 0.f, 0.f};
        S[kb] = __builtin_amdgcn_mfma_f32_16x16x32_bf16(qf, kf, z, 0, 0, 0);
    }
    __syncthreads();   // kS dead; region becomes Pb

    // ---- bias + mask + softmax stats; store raw exp (normalize at epilogue)
    f32x4 rinvv;
#pragma unroll
    for (int i = 0; i < 4; ++i) {
        int m = lg * 4 + i;
        int gi = ti0 + wave * 2 + (m >> 3);
        int gj = tj0 + (m & 7);
        int si = min(max(gi - 3, 0), 57), sj = min(max(gj - 3, 0), 57);
        bool cv = (unsigned)(hc0 + lr - sj) < 7u;
        int rjc = min(max(hc0 + lr - gj + 6, 0), 12);
        float mxi = -INFINITY;
#pragma unroll
        for (int kb = 0; kb < 14; ++kb) {
            bool rv = (unsigned)(hr0 + kb - si) < 7u;
            int ric = min(max(hr0 + kb - gi + 6, 0), 12);
            float bias = rpbs[rjc + ric * 13];
            float s = (rv && cv) ? S[kb][i] + bias : -1e30f;
            S[kb][i] = s;
            mxi = fmaxf(mxi, s);
        }
        mxi = fmaxf(mxi, __shfl_xor(mxi, 1));
        mxi = fmaxf(mxi, __shfl_xor(mxi, 2));
        mxi = fmaxf(mxi, __shfl_xor(mxi, 4));
        mxi = fmaxf(mxi, __shfl_xor(mxi, 8));
        float smi = 0.0f;
#pragma unroll
        for (int kb = 0; kb < 14; ++kb) {
            float e = __expf(S[kb][i] - mxi);
            S[kb][i] = e;
            smi += e;
        }
        smi += __shfl_xor(smi, 1);
        smi += __shfl_xor(smi, 2);
        smi += __shfl_xor(smi, 4);
        smi += __shfl_xor(smi, 8);
        rinvv[i] = 1.0f / smi;
    }

    // ---- PV in 4 rounds through wave-private Pb (raw exp, bf16)
    f32x4 O[2] = {};
#pragma unroll
    for (int r = 0; r < 4; ++r) {
        const int nk = (r < 3) ? 4 : 2;
#pragma unroll
        for (int i = 0; i < 4; ++i) {
            int m = lg * 4 + i;
#pragma unroll
            for (int kbl = 0; kbl < 4; ++kbl) {
                if (kbl < nk)
                    Pb[(wave * 16 + m) * 72 + kbl * 16 + lr] = f2bf(S[r * 4 + kbl][i]);
            }
        }
#pragma unroll
        for (int ksl = 0; ksl < 2; ++ksl) {
            if (ksl * 2 < nk) {
                bf16x8 pf = *(const bf16x8*)&Pb[(wave * 16 + lr) * 72 + ksl * 32 + lg * 8];
#pragma unroll
                for (int nb = 0; nb < 2; ++nb) {
                    int ch = nb * 16 + lr;
                    int sw = (ch >> 3) << 3;
                    int tbase = (r * 64 + ksl * 32 + lg * 8) ^ sw;   // 8-contig, aligned
                    bf16x8 vf = *(const bf16x8*)&vT[ch * 232 + tbase];
                    O[nb] = __builtin_amdgcn_mfma_f32_16x16x32_bf16(pf, vf, O[nb], 0, 0, 0);
                }
            }
        }
    }

    // ---- write out (C layout), apply deferred 1/sum
#pragma unroll
    for (int i = 0; i < 4; ++i) {
        int m = lg * 4 + i;
        int gi = ti0 + wave * 2 + (m >> 3);
        int gj = tj0 + (m & 7);
        size_t t = ((size_t)(bb + gi * 64 + gj)) * 128 + h * 32;
        out[t + lr]      = f2bf(O[0][i] * rinvv[i]);
        out[t + 16 + lr] = f2bf(O[1][i] * rinvv[i]);
    }
}

// ---------------- D4: tail = Wp + res + LN3 + W1 + GELU + W2 + res ----------
// Block = 16 tokens, 4 waves, 1024 blocks.
__global__ __launch_bounds__(256) void tail_kernel(
    const unsigned short* __restrict__ attnh, // [TOK][128] bf16
    const unsigned short* __restrict__ WtP,   // [128][128]
    const unsigned short* __restrict__ W1t,   // [512][128]
    const unsigned short* __restrict__ W2t,   // [128][512]
    const float* __restrict__ bp, const float* __restrict__ bm1, const float* __restrict__ bm2,
    const float* __restrict__ resk,           // key_value f32 (shortcut)
    const float* __restrict__ g3, const float* __restrict__ b3,
    float* __restrict__ dout)
{
    __shared__ float xs[16][132];                           // x, f32
    __shared__ __align__(16) unsigned short xnS[16 * 136];  // LN3(x), bf16
    __shared__ __align__(16) unsigned short hS[16 * 520];   // gelu(xn@W1), bf16
    const int tid = threadIdx.x;
    const int wave = tid >> 6, lane = tid & 63;
    const int lr = lane & 15, lg = lane >> 4;
    const int m0 = blockIdx.x * 16;

#pragma unroll
    for (int t = 0; t < 2; ++t) {
        int colt = wave + 4 * t;
        int tok = m0 + lr;
        f32x4 acc = {0.f, 0.f, 0.f, 0.f};
#pragma unroll
        for (int kk = 0; kk < 4; ++kk) {
            bf16x8 af = *(const bf16x8*)(attnh + (size_t)tok * 128 + kk * 32 + lg * 8);
            bf16x8 wf = *(const bf16x8*)(WtP + (size_t)(colt * 16 + lr) * 128 + kk * 32 + lg * 8);
            acc = __builtin_amdgcn_mfma_f32_16x16x32_bf16(af, wf, acc, 0, 0, 0);
        }
        int gc = colt * 16 + lr;
        float bs = bp[gc];
#pragma unroll
        for (int r = 0; r < 4; ++r) {
            int row = lg * 4 + r;
            xs[row][gc] = acc[r] + bs + resk[(size_t)(m0 + row) * 128 + gc];
        }
    }
    __syncthreads();

    {
        const int r = tid >> 4, t16 = tid & 15;
        float vals[8];
#pragma unroll
        for (int jj = 0; jj < 8; ++jj) vals[jj] = xs[r][t16 * 8 + jj];
        float s = 0.0f;
#pragma unroll
        for (int jj = 0; jj < 8; ++jj) s += vals[jj];
        s += __shfl_xor(s, 1); s += __shfl_xor(s, 2);
        s += __shfl_xor(s, 4); s += __shfl_xor(s, 8);
        float mean = s * (1.0f / 128.0f);
        float vv = 0.0f;
#pragma unroll
        for (int jj = 0; jj < 8; ++jj) { float d = vals[jj] - mean; vv += d * d; }
        vv += __shfl_xor(vv, 1); vv += __shfl_xor(vv, 2);
        vv += __shfl_xor(vv, 4); vv += __shfl_xor(vv, 8);
        float rs = rsqrtf(vv * (1.0f / 128.0f) + 1e-5f);
        float4 ga = *(const float4*)(g3 + t16 * 8);
        float4 gb = *(const float4*)(g3 + t16 * 8 + 4);
        float4 ba = *(const float4*)(b3 + t16 * 8);
        float4 bbv = *(const float4*)(b3 + t16 * 8 + 4);
        ushort4 oa, ob;
        oa.x = f2bf((vals[0] - mean) * rs * ga.x + ba.x);
        oa.y = f2bf((vals[1] - mean) * rs * ga.y + ba.y);
        oa.z = f2bf((vals[2] - mean) * rs * ga.z + ba.z);
        oa.w = f2bf((vals[3] - mean) * rs * ga.w + ba.w);
        ob.x = f2bf((vals[4] - mean) * rs * gb.x + bbv.x);
        ob.y = f2bf((vals[5] - mean) * rs * gb.y + bbv.y);
        ob.z = f2bf((vals[6] - mean) * rs * gb.z + bbv.z);
        ob.w = f2bf((vals[7] - mean) * rs * gb.w + bbv.w);
        *(ushort4*)&xnS[r * 136 + t16 * 8] = oa;
        *(ushort4*)&xnS[r * 136 + t16 * 8 + 4] = ob;
    }
    __syncthreads();

#pragma unroll
    for (int t = 0; t < 8; ++t) {
        int colt = wave + 4 * t;
        f32x4 acc = {0.f, 0.f, 0.f, 0.f};
#pragma unroll
        for (int kk = 0; kk < 4; ++kk) {
            bf16x8 wf = *(const bf16x8*)(W1t + (size_t)(colt * 16 + lr) * 128 + kk * 32 + lg * 8);
            bf16x8 xf = *(const bf16x8*)&xnS[lr * 136 + kk * 32 + lg * 8];
            acc = __builtin_amdgcn_mfma_f32_16x16x32_bf16(wf, xf, acc, 0, 0, 0);
        }
        int chb = colt * 16 + lg * 4;
        float4 bs = *(const float4*)(bm1 + chb);
        ushort4 pk;
        pk.x = f2bf(gelu_exact(acc[0] + bs.x));
        pk.y = f2bf(gelu_exact(acc[1] + bs.y));
        pk.z = f2bf(gelu_exact(acc[2] + bs.z));
        pk.w = f2bf(gelu_exact(acc[3] + bs.w));
        *(ushort4*)&hS[lr * 520 + chb] = pk;
    }
    __syncthreads();

#pragma unroll
    for (int t = 0; t < 2; ++t) {
        int colt = wave + 4 * t;
        f32x4 acc = {0.f, 0.f, 0.f, 0.f};
#pragma unroll
        for (int kk = 0; kk < 16; ++kk) {
            bf16x8 hf = *(const bf16x8*)&hS[lr * 520 + kk * 32 + lg * 8];
            bf16x8 wf = *(const bf16x8*)(W2t + (size_t)(colt * 16 + lr) * 512 + kk * 32 + lg * 8);
            acc = __builtin_amdgcn_mfma_f32_16x16x32_bf16(hf, wf, acc, 0, 0, 0);
        }
        int gc = colt * 16 + lr;
        float bs = bm2[gc];
#pragma unroll
        for (int r = 0; r < 4; ++r) {
            int row = lg * 4 + r;
            dout[(size_t)(m0 + row) * 128 + gc] = acc[r] + bs + xs[row][gc];
        }
    }
}

extern "C" void kernel_launch(void* const* d_in, const int* in_sizes, int n_in,
                              void* d_out, int out_size, void* d_ws, size_t ws_size,
                              hipStream_t stream) {
    const float* query     = (const float*)d_in[0];
    const float* key_value = (const float*)d_in[1];
    const float* g1 = (const float*)d_in[2];
    const float* b1 = (const float*)d_in[3];
    const float* g2 = (const float*)d_in[4];
    const float* b2 = (const float*)d_in[5];
    const float* g3 = (const float*)d_in[6];
    const float* b3 = (const float*)d_in[7];
    const float* Wq  = (const float*)d_in[8];
    const float* bq  = (const float*)d_in[9];
    const float* Wkv = (const float*)d_in[10];
    const float* bkv = (const float*)d_in[11];
    const float* Wp  = (const float*)d_in[12];
    const float* bp  = (const float*)d_in[13];
    const float* rpb = (const float*)d_in[14];
    const float* W1  = (const float*)d_in[15];
    const float* bm1 = (const float*)d_in[16];
    const float* W2  = (const float*)d_in[17];
    const float* bm2 = (const float*)d_in[18];

    char* ws = (char*)d_ws;
    unsigned short* qbh   = (unsigned short*)(ws + 0);         // 4 MB bf16 [TOK][128]
    unsigned short* kbh   = (unsigned short*)(ws + 4194304);   // 4 MB bf16 [TOK][128]
    unsigned short* vbh   = (unsigned short*)(ws + 8388608);   // 4 MB bf16 [TOK][128]
    unsigned short* attnh = (unsigned short*)(ws + 12582912);  // 4 MB bf16 [TOK][128]
    unsigned short* Wt    = (unsigned short*)(ws + 16777216);  // 384 KB bf16 transposed
    // attn halo staging may read <=2 tokens past kbh/vbh -> lands in vbh/attnh
    // (mapped workspace, finite bf16, masked before softmax)

    const float qscale = 0.17677669529663687f;  // HD^-0.5

    wtrans_kernel<<<192, 256, 0, stream>>>(Wq, Wkv, Wp, W1, W2, Wt);
    qkvln_kernel<<<1024, 256, 0, stream>>>(query, key_value, g1, b1, g2, b2,
                                           Wt, bq, bkv, qbh, kbh, vbh, qscale);
    nat_attn<<<1024, 256, 0, stream>>>(qbh, kbh, vbh, rpb, attnh);
    tail_kernel<<<1024, 256, 0, stream>>>(attnh, Wt + 49152, Wt + 65536, Wt + 131072,
                                          bp, bm1, bm2, key_value, g3, b3, (float*)d_out);
}